// Round 2
// baseline (1085.217 us; speedup 1.0000x reference)
//
#include <hip/hip_runtime.h>
#include <math.h>

#define NROWS 16384
#define DDIM  1024
#define HIDD  4096
// IN_DIM = 4097 handled as K=4096 + last-row epilogue term

typedef __bf16 bf16;
typedef bf16 bf16x8 __attribute__((ext_vector_type(8)));
typedef bf16 bf16x4 __attribute__((ext_vector_type(4)));
typedef float f32x4 __attribute__((ext_vector_type(4)));

__device__ __forceinline__ float gelu_erf(float x) {
  return 0.5f * x * (1.0f + erff(x * 0.70710678118654752f));
}

__device__ __forceinline__ void gld16(const bf16* g, bf16* l) {
  __builtin_amdgcn_global_load_lds(
      (const __attribute__((address_space(1))) void*)g,
      (__attribute__((address_space(3))) void*)l, 16, 0, 0);
}

// ---------------- elementwise cast fp32 -> bf16 (vector4) ----------------
__global__ __launch_bounds__(256) void cast_bf16_k(const float* __restrict__ in,
                                                   bf16* __restrict__ out) {
  size_t i = (size_t)blockIdx.x * blockDim.x + threadIdx.x;
  float4 v = ((const float4*)in)[i];
  bf16x4 o = {(bf16)v.x, (bf16)v.y, (bf16)v.z, (bf16)v.w};
  ((bf16x4*)out)[i] = o;
}

// ---------------- tiled transpose + cast: in[R][C] fp32 -> out[C][R] bf16 ----
__global__ __launch_bounds__(256) void transpose_cast_k(const float* __restrict__ in,
                                                        bf16* __restrict__ out,
                                                        int R, int C) {
  __shared__ float tile[32][33];
  int bx = blockIdx.x * 32, by = blockIdx.y * 32;
  int tx = threadIdx.x, ty = threadIdx.y;
  #pragma unroll
  for (int i = ty; i < 32; i += 8)
    tile[i][tx] = in[(size_t)(by + i) * C + bx + tx];
  __syncthreads();
  #pragma unroll
  for (int i = ty; i < 32; i += 8)
    out[(size_t)(bx + i) * R + by + tx] = (bf16)tile[tx][i];
}

// ---------------- fused row op: had/diff/s + LayerNorm -> x_bf16, s_ln -------
__global__ __launch_bounds__(256) void rowfuse_k(
    const float* __restrict__ zA, const float* __restrict__ zB,
    const bf16* __restrict__ t, const float* __restrict__ lng,
    const float* __restrict__ lnb, bf16* __restrict__ x,
    float* __restrict__ s_ln) {
  int row = blockIdx.x, tid = threadIdx.x;
  float4 a4 = ((const float4*)(zA + (size_t)row * DDIM))[tid];
  float4 b4 = ((const float4*)(zB + (size_t)row * DDIM))[tid];
  bf16x4 t4 = ((const bf16x4*)(t + (size_t)row * DDIM))[tid];
  float av[4] = {a4.x, a4.y, a4.z, a4.w};
  float bv[4] = {b4.x, b4.y, b4.z, b4.w};
  float hv[4], dv[4];
  float s1 = 0.f, s2 = 0.f, sd = 0.f;
  #pragma unroll
  for (int j = 0; j < 4; j++) {
    hv[j] = av[j] * bv[j];
    dv[j] = fabsf(av[j] - bv[j]);
    s1 += av[j] + bv[j] + hv[j] + dv[j];
    s2 += av[j]*av[j] + bv[j]*bv[j] + hv[j]*hv[j] + dv[j]*dv[j];
    sd += (float)t4[j] * bv[j];
  }
  #pragma unroll
  for (int off = 32; off > 0; off >>= 1) {
    s1 += __shfl_xor(s1, off, 64);
    s2 += __shfl_xor(s2, off, 64);
    sd += __shfl_xor(sd, off, 64);
  }
  __shared__ float red[3][4];
  int wave = tid >> 6;
  if ((tid & 63) == 0) { red[0][wave] = s1; red[1][wave] = s2; red[2][wave] = sd; }
  __syncthreads();
  s1 = red[0][0] + red[0][1] + red[0][2] + red[0][3];
  s2 = red[1][0] + red[1][1] + red[1][2] + red[1][3];
  float s = red[2][0] + red[2][1] + red[2][2] + red[2][3];
  const float inv = 1.0f / 4097.0f;
  float mu = (s1 + s) * inv;
  float var = (s2 + s * s) * inv - mu * mu;
  float rs = rsqrtf(var + 1e-5f);
  bf16* xr = x + (size_t)row * 4096;
  #define WRITE_SEG(si, vals)                                            \
  {                                                                      \
    float4 gg = ((const float4*)lng)[(si)*256 + tid];                    \
    float4 bb = ((const float4*)lnb)[(si)*256 + tid];                    \
    const float* gp = (const float*)&gg;                                 \
    const float* bp = (const float*)&bb;                                 \
    bf16x4 o;                                                            \
    _Pragma("unroll") for (int j = 0; j < 4; j++)                        \
        o[j] = (bf16)((vals[j] - mu) * rs * gp[j] + bp[j]);              \
    ((bf16x4*)xr)[(si)*256 + tid] = o;                                   \
  }
  WRITE_SEG(0, av)
  WRITE_SEG(1, bv)
  WRITE_SEG(2, hv)
  WRITE_SEG(3, dv)
  #undef WRITE_SEG
  if (tid == 0) s_ln[row] = (s - mu) * rs * lng[4096] + lnb[4096];
}

// ---------------- bf16 MFMA GEMM, 128x128 tile (EPI 0 and 2) ----------------
// EPI 0: store bf16 (t = zA@bilinear)
// EPI 2: v += b2[col]; gelu; store fp32 (out)
template <int EPI>
__global__ __launch_bounds__(256) void gemm_bt_k(
    const bf16* __restrict__ A, const bf16* __restrict__ B, int K, int Nout,
    void* __restrict__ Cout, const float* __restrict__ bias,
    const float* __restrict__ srow, const float* __restrict__ wlast) {
  __shared__ alignas(16) bf16 As[128 * 64];
  __shared__ alignas(16) bf16 Bs[128 * 64];
  const int tid = threadIdx.x;
  const int wave = tid >> 6, lane = tid & 63;
  const int wm = wave >> 1, wn = wave & 1;
  const int lrow = lane & 15, quad = lane >> 4;
  const size_t rowA0 = (size_t)blockIdx.y * 128;
  const size_t rowB0 = (size_t)blockIdx.x * 128;

  f32x4 acc[4][4] = {};

  const int lchunk = (tid & 7) ^ ((tid >> 3) & 7);
  const bf16* gA = A + (rowA0 + (tid >> 3)) * (size_t)K + lchunk * 8;
  const bf16* gB = B + (rowB0 + (tid >> 3)) * (size_t)K + lchunk * 8;

  for (int kb = 0; kb < K; kb += 64) {
    const bf16* pa = gA + kb;
    const bf16* pb = gB + kb;
    #pragma unroll
    for (int it = 0; it < 4; it++) {
      gld16(pa + (size_t)it * 32 * K, As + it * 2048 + wave * 512);
      gld16(pb + (size_t)it * 32 * K, Bs + it * 2048 + wave * 512);
    }
    __syncthreads();
    #pragma unroll
    for (int kk = 0; kk < 2; kk++) {
      const int cla = ((kk * 4 + quad) ^ (lrow & 7)) * 8;
      bf16x8 af[4], bfr[4];
      #pragma unroll
      for (int mi = 0; mi < 4; mi++)
        af[mi] = *(const bf16x8*)(As + (wm * 64 + mi * 16 + lrow) * 64 + cla);
      #pragma unroll
      for (int ni = 0; ni < 4; ni++)
        bfr[ni] = *(const bf16x8*)(Bs + (wn * 64 + ni * 16 + lrow) * 64 + cla);
      #pragma unroll
      for (int mi = 0; mi < 4; mi++)
        #pragma unroll
        for (int ni = 0; ni < 4; ni++)
          acc[mi][ni] = __builtin_amdgcn_mfma_f32_16x16x32_bf16(af[mi], bfr[ni], acc[mi][ni], 0, 0, 0);
    }
    __syncthreads();
  }

  const size_t ldc = (size_t)Nout;
  #pragma unroll
  for (int mi = 0; mi < 4; mi++) {
    size_t row = rowA0 + wm * 64 + mi * 16 + quad * 4;
    float srv[4];
    if (EPI == 1) {
      #pragma unroll
      for (int r = 0; r < 4; r++) srv[r] = srow[row + r];
    }
    #pragma unroll
    for (int ni = 0; ni < 4; ni++) {
      size_t col = rowB0 + wn * 64 + ni * 16 + lrow;
      float bvv = (EPI != 0) ? bias[col] : 0.0f;
      float wl = (EPI == 1) ? wlast[col] : 0.0f;
      #pragma unroll
      for (int r = 0; r < 4; r++) {
        float v = acc[mi][ni][r];
        if (EPI == 1) v += bvv + srv[r] * wl;
        if (EPI == 2) v += bvv;
        if (EPI != 0) v = gelu_erf(v);
        size_t idx = (row + r) * ldc + col;
        if (EPI == 2) ((float*)Cout)[idx] = v;
        else ((bf16*)Cout)[idx] = (bf16)v;
      }
    }
  }
}

// ---------------- 256x256-tile 8-phase bf16 GEMM (EPI1: h = gelu(x@W1+...)) --
// 512 threads = 8 waves (2M x 4N); wave tile 128x64; BK=64 as 2 K-halves of 32.
// LDS 128 KiB: [2 dbuf][2 Khalf] x {A,B} x [256 rows][32 k] bf16.
// Counted vmcnt(4) at phases 4/8 only (T3+T4); setprio around MFMA (T5);
// XOR-swizzled chunks, 0 bank conflicts (T2).
// NEW r2: (a) XCD rectangle swizzle -- 1-D grid, each XCD's 32 concurrent
// blocks form a 4-row x 8-col rectangle so its L2 working set is 4 A-panels +
// 8 B-panels (24 MB inflow/32 blocks) instead of the default mapping's
// 2-cols x all-rows (16 streaming A-panels thrash the 4 MB L2 and duplicate
// A into every XCD). (b) forced lgkmcnt(0) replaced by compiler-only fences:
// compiler emits counted lgkmcnt per MFMA operand, overlapping LDS service
// with the MFMA ramp (B-frag reads issued first, so MFMA 0 waits on 3 of 10).
// Staging ledger (iteration computes tiles 2i (buf0) and 2i+1 (buf1)):
//   ph1: A(2i+1).Kh1  ph2: B(2i+1).Kh1
//   ph3: A(2i+2).Kh0  ph4: B(2i+2).Kh0  + vmcnt(4)
//   ph5: A(2i+2).Kh1  ph6: B(2i+2).Kh1
//   ph7: A(2i+3).Kh0  ph8: B(2i+3).Kh0  + vmcnt(4)
// vmcnt(4) at ph4 leaves ph3/ph4 units in flight => all regions read in
// ph5..ph8 complete; ph8's leaves ph7/ph8 => next ph1..ph4 complete. Tail
// staging wraps ko&(K-1) (never skipped => vmcnt counts stay exact).
#define CFENCE asm volatile("" ::: "memory")
__global__ __launch_bounds__(512, 2) void gemm256_epi1_k(
    const bf16* __restrict__ A, const bf16* __restrict__ B, int K, int Nout,
    bf16* __restrict__ Cout, const float* __restrict__ bias,
    const float* __restrict__ srow, const float* __restrict__ wlast) {
  __shared__ alignas(16) bf16 As[2][2][8192];
  __shared__ alignas(16) bf16 Bs[2][2][8192];
  const int tid = threadIdx.x;
  const int wave = tid >> 6, lane = tid & 63;
  const int wm = wave >> 2, wn = wave & 3;
  const int lrow = lane & 15, quad = lane >> 4;
  const int cswz = ((quad ^ ((lrow >> 1) & 3)) << 3);

  // XCD rectangle swizzle (grid fixed at 16 cols x nrow rows, nrow%16==0):
  // hw round-robins wg id%8 -> XCD; give XCD x two stacked passes of a
  // 4x8 rectangle: by = pass*16 + (xcd>>1)*4 + rrow, bx = (xcd&1)*8 + rcol.
  const int id = blockIdx.x;
  const int nrow = gridDim.x >> 4;
  int bxt, byt;
  if ((nrow & 15) == 0) {
    const int xcd = id & 7, k = id >> 3;
    const int rect = k >> 5, pos = k & 31;
    byt = rect * 16 + ((xcd >> 1) << 2) + (pos >> 3);
    bxt = ((xcd & 1) << 3) + (pos & 7);
  } else {
    bxt = id & 15;
    byt = id >> 4;
  }
  const size_t rowA0 = (size_t)byt * 256;
  const size_t rowB0 = (size_t)bxt * 256;
  const int Kmask = K - 1;

  // staging: thread t -> row t>>2 (of 128), physical chunk t&3; fetch the
  // logical chunk that belongs there (pre-swizzled global source, rule #21)
  const int sr = tid >> 2;
  const int sq = (tid & 3) ^ ((sr >> 1) & 3);
  const bf16* gA = A + (rowA0 + sr) * (size_t)K + sq * 8;
  const bf16* gB = B + (rowB0 + sr) * (size_t)K + sq * 8;
  const size_t rstep = 128 * (size_t)K;
  const int wofs = wave * 512;  // 64 lanes x 8 bf16 per wave per gld

  f32x4 acc[8][4] = {};

#define STG_A(b, h, ko) { const bf16* s_ = gA + ((ko) & Kmask);          \
    gld16(s_, &As[b][h][wofs]); gld16(s_ + rstep, &As[b][h][4096 + wofs]); }
#define STG_B(b, h, ko) { const bf16* s_ = gB + ((ko) & Kmask);          \
    gld16(s_, &Bs[b][h][wofs]); gld16(s_ + rstep, &Bs[b][h][4096 + wofs]); }

  // prologue: tile0 (Kh0+Kh1) + tile1.Kh0; wait tile0, keep tile1.Kh0 in flight
  STG_A(0, 0, 0)  STG_B(0, 0, 0)
  STG_A(0, 1, 32) STG_B(0, 1, 32)
  STG_A(1, 0, 64) STG_B(1, 0, 64)
  asm volatile("s_waitcnt vmcnt(4)" ::: "memory");
  __builtin_amdgcn_s_barrier();
  CFENCE;

  bf16x8 af[8], bfr[2];
  const int arow = wm * 128 + lrow;
  const int brow = wn * 64 + lrow;

#define LD_A(b, h) { _Pragma("unroll") for (int mi = 0; mi < 8; mi++)    \
    af[mi] = *(const bf16x8*)(&As[b][h][(arow + mi * 16) * 32 + cswz]); }
#define LD_B(b, h, nlo) { _Pragma("unroll") for (int nj = 0; nj < 2; nj++) \
    bfr[nj] = *(const bf16x8*)(&Bs[b][h][(brow + ((nlo) + nj) * 16) * 32 + cswz]); }
#define MFMA_HALF(nlo) { _Pragma("unroll") for (int mi = 0; mi < 8; mi++) {           \
    acc[mi][nlo] = __builtin_amdgcn_mfma_f32_16x16x32_bf16(af[mi], bfr[0], acc[mi][nlo], 0, 0, 0);       \
    acc[mi][(nlo)+1] = __builtin_amdgcn_mfma_f32_16x16x32_bf16(af[mi], bfr[1], acc[mi][(nlo)+1], 0, 0, 0); } }
#define PH(bufc, khc, nlo, LOADA, STAGE, VW) {                           \
    LD_B(bufc, khc, nlo)                                                 \
    if (LOADA) LD_A(bufc, khc)                                           \
    STAGE                                                                \
    CFENCE;                                                              \
    __builtin_amdgcn_s_barrier();                                        \
    CFENCE;                                                              \
    __builtin_amdgcn_s_setprio(1);                                       \
    MFMA_HALF(nlo)                                                       \
    __builtin_amdgcn_s_setprio(0);                                       \
    CFENCE;                                                              \
    VW                                                                   \
    __builtin_amdgcn_s_barrier();                                        \
    CFENCE; }

  const int NI = K >> 7;
  int kb = 0;
  #pragma unroll 1
  for (int i = 0; i < NI; ++i, kb += 128) {
    PH(0, 0, 0, 1, STG_A(1, 1, kb + 96), )
    PH(0, 0, 2, 0, STG_B(1, 1, kb + 96), )
    PH(0, 1, 0, 1, STG_A(0, 0, kb + 128), )
    PH(0, 1, 2, 0, STG_B(0, 0, kb + 128),
       asm volatile("s_waitcnt vmcnt(4)" ::: "memory");)
    PH(1, 0, 0, 1, STG_A(0, 1, kb + 160), )
    PH(1, 0, 2, 0, STG_B(0, 1, kb + 160), )
    PH(1, 1, 0, 1, STG_A(1, 0, kb + 192), )
    PH(1, 1, 2, 0, STG_B(1, 0, kb + 192),
       asm volatile("s_waitcnt vmcnt(4)" ::: "memory");)
  }
  // drain wrapped tail prefetches before LDS goes away / epilogue
  asm volatile("s_waitcnt vmcnt(0)" ::: "memory");
#undef PH
#undef MFMA_HALF
#undef LD_B
#undef LD_A
#undef STG_B
#undef STG_A

  const size_t ldc = (size_t)Nout;
  #pragma unroll
  for (int mi = 0; mi < 8; mi++) {
    size_t row = rowA0 + wm * 128 + mi * 16 + quad * 4;
    float srv[4];
    #pragma unroll
    for (int r = 0; r < 4; r++) srv[r] = srow[row + r];
    #pragma unroll
    for (int ni = 0; ni < 4; ni++) {
      size_t col = rowB0 + wn * 64 + ni * 16 + lrow;
      float bvv = bias[col];
      float wl = wlast[col];
      #pragma unroll
      for (int r = 0; r < 4; r++) {
        float v = acc[mi][ni][r] + bvv + srv[r] * wl;
        v = gelu_erf(v);
        Cout[(row + r) * ldc + col] = (bf16)v;
      }
    }
  }
}

extern "C" void kernel_launch(void* const* d_in, const int* in_sizes, int n_in,
                              void* d_out, int out_size, void* d_ws, size_t ws_size,
                              hipStream_t stream) {
  const float* zA  = (const float*)d_in[0];
  const float* zB  = (const float*)d_in[1];
  const float* bil = (const float*)d_in[2];
  const float* lng = (const float*)d_in[3];
  const float* lnb = (const float*)d_in[4];
  const float* W1  = (const float*)d_in[5];
  const float* b1  = (const float*)d_in[6];
  const float* W2  = (const float*)d_in[7];
  const float* b2  = (const float*)d_in[8];
  float* out = (float*)d_out;

  // ---- workspace layout (adaptive row-chunking) ----
  char* ws = (char*)d_ws;
  const size_t SZ_BILT = (size_t)DDIM * DDIM * 2;        //  2 MiB
  const size_t SZ_W1T  = (size_t)4096 * 4096 * 2;        // 32 MiB
  const size_t SZ_W2T  = (size_t)DDIM * HIDD * 2;        //  8 MiB
  const size_t PERSIST = SZ_BILT + SZ_W1T + SZ_W2T;      // 42 MiB

  int C = 0;
  for (int cand = NROWS; cand >= 512; cand >>= 1) {
    size_t need = PERSIST + (size_t)16384 * cand + (size_t)4 * cand + 1024;
    if (need <= ws_size) { C = cand; break; }
  }
  if (C == 0) return;  // workspace hopelessly small — leave poison (fail loudly)

  bf16* bilT = (bf16*)ws;
  bf16* W1T  = (bf16*)(ws + SZ_BILT);
  bf16* W2T  = (bf16*)(ws + SZ_BILT + SZ_W1T);
  char* dyn  = ws + PERSIST;
  bf16*  r1    = (bf16*)dyn;                              // region1: zA_bf|t_bf -> h
  bf16*  zA_bf = r1;                                      // [C,1024] bf16
  bf16*  t_bf  = r1 + (size_t)C * 1024;                   // [C,1024] bf16
  bf16*  h_bf  = r1;                                      // [C,4096] bf16 (overlays after rowfuse)
  bf16*  x_bf  = (bf16*)(dyn + (size_t)8192 * C);         // [C,4096] bf16
  float* s_ln  = (float*)(dyn + (size_t)16384 * C);       // [C] fp32

  dim3 tb(32, 8);
  transpose_cast_k<<<dim3(DDIM / 32, DDIM / 32), tb, 0, stream>>>(bil, bilT, DDIM, DDIM);
  transpose_cast_k<<<dim3(HIDD / 32, 4096 / 32), tb, 0, stream>>>(W1, W1T, 4096, HIDD);
  transpose_cast_k<<<dim3(DDIM / 32, HIDD / 32), tb, 0, stream>>>(W2, W2T, HIDD, DDIM);

  for (int r0 = 0; r0 < NROWS; r0 += C) {
    const float* zAc = zA + (size_t)r0 * DDIM;
    const float* zBc = zB + (size_t)r0 * DDIM;

    // cast zA chunk -> bf16
    cast_bf16_k<<<(C * DDIM / 4) / 256, 256, 0, stream>>>(zAc, zA_bf);

    // t = zA @ bilinear   [C, DDIM]
    gemm_bt_k<0><<<dim3(DDIM / 128, C / 128), 256, 0, stream>>>(
        zA_bf, bilT, DDIM, DDIM, t_bf, nullptr, nullptr, nullptr);

    // had/diff/s + LayerNorm -> x_bf, s_ln
    rowfuse_k<<<C, 256, 0, stream>>>(zAc, zBc, t_bf, lng, lnb, x_bf, s_ln);

    // h = gelu(x @ W1 + b1 + s_ln*W1_last)  [C, HIDD] — 256² 8-phase kernel
    // 1-D grid so the XCD rectangle swizzle controls placement exactly
    gemm256_epi1_k<<<dim3((HIDD / 256) * (C / 256)), 512, 0, stream>>>(
        x_bf, W1T, 4096, HIDD, h_bf, b1, s_ln, W1 + (size_t)4096 * HIDD);

    // out = gelu(h @ W2 + b2)   [C, DDIM]
    gemm_bt_k<2><<<dim3(DDIM / 128, C / 128), 256, 0, stream>>>(
        h_bf, W2T, 4096, DDIM, out + (size_t)r0 * DDIM, b2, nullptr, nullptr);
  }
}

// Round 3
// 1053.806 us; speedup vs baseline: 1.0298x; 1.0298x over previous
//
#include <hip/hip_runtime.h>
#include <math.h>

#define NROWS 16384
#define DDIM  1024
#define HIDD  4096
// IN_DIM = 4097 handled as K=4096 + last-row epilogue term

typedef __bf16 bf16;
typedef bf16 bf16x8 __attribute__((ext_vector_type(8)));
typedef bf16 bf16x4 __attribute__((ext_vector_type(4)));
typedef float f32x4 __attribute__((ext_vector_type(4)));

__device__ __forceinline__ float gelu_erf(float x) {
  return 0.5f * x * (1.0f + erff(x * 0.70710678118654752f));
}

__device__ __forceinline__ void gld16(const bf16* g, bf16* l) {
  __builtin_amdgcn_global_load_lds(
      (const __attribute__((address_space(1))) void*)g,
      (__attribute__((address_space(3))) void*)l, 16, 0, 0);
}

// ---------------- elementwise cast fp32 -> bf16 (vector4) ----------------
__global__ __launch_bounds__(256) void cast_bf16_k(const float* __restrict__ in,
                                                   bf16* __restrict__ out) {
  size_t i = (size_t)blockIdx.x * blockDim.x + threadIdx.x;
  float4 v = ((const float4*)in)[i];
  bf16x4 o = {(bf16)v.x, (bf16)v.y, (bf16)v.z, (bf16)v.w};
  ((bf16x4*)out)[i] = o;
}

// ---------------- tiled transpose + cast: in[R][C] fp32 -> out[C][R] bf16 ----
__global__ __launch_bounds__(256) void transpose_cast_k(const float* __restrict__ in,
                                                        bf16* __restrict__ out,
                                                        int R, int C) {
  __shared__ float tile[32][33];
  int bx = blockIdx.x * 32, by = blockIdx.y * 32;
  int tx = threadIdx.x, ty = threadIdx.y;
  #pragma unroll
  for (int i = ty; i < 32; i += 8)
    tile[i][tx] = in[(size_t)(by + i) * C + bx + tx];
  __syncthreads();
  #pragma unroll
  for (int i = ty; i < 32; i += 8)
    out[(size_t)(bx + i) * R + by + tx] = (bf16)tile[tx][i];
}

// ---------------- fused row op: had/diff/s + LayerNorm -> x_bf16, s_ln -------
__global__ __launch_bounds__(256) void rowfuse_k(
    const float* __restrict__ zA, const float* __restrict__ zB,
    const bf16* __restrict__ t, const float* __restrict__ lng,
    const float* __restrict__ lnb, bf16* __restrict__ x,
    float* __restrict__ s_ln) {
  int row = blockIdx.x, tid = threadIdx.x;
  float4 a4 = ((const float4*)(zA + (size_t)row * DDIM))[tid];
  float4 b4 = ((const float4*)(zB + (size_t)row * DDIM))[tid];
  bf16x4 t4 = ((const bf16x4*)(t + (size_t)row * DDIM))[tid];
  float av[4] = {a4.x, a4.y, a4.z, a4.w};
  float bv[4] = {b4.x, b4.y, b4.z, b4.w};
  float hv[4], dv[4];
  float s1 = 0.f, s2 = 0.f, sd = 0.f;
  #pragma unroll
  for (int j = 0; j < 4; j++) {
    hv[j] = av[j] * bv[j];
    dv[j] = fabsf(av[j] - bv[j]);
    s1 += av[j] + bv[j] + hv[j] + dv[j];
    s2 += av[j]*av[j] + bv[j]*bv[j] + hv[j]*hv[j] + dv[j]*dv[j];
    sd += (float)t4[j] * bv[j];
  }
  #pragma unroll
  for (int off = 32; off > 0; off >>= 1) {
    s1 += __shfl_xor(s1, off, 64);
    s2 += __shfl_xor(s2, off, 64);
    sd += __shfl_xor(sd, off, 64);
  }
  __shared__ float red[3][4];
  int wave = tid >> 6;
  if ((tid & 63) == 0) { red[0][wave] = s1; red[1][wave] = s2; red[2][wave] = sd; }
  __syncthreads();
  s1 = red[0][0] + red[0][1] + red[0][2] + red[0][3];
  s2 = red[1][0] + red[1][1] + red[1][2] + red[1][3];
  float s = red[2][0] + red[2][1] + red[2][2] + red[2][3];
  const float inv = 1.0f / 4097.0f;
  float mu = (s1 + s) * inv;
  float var = (s2 + s * s) * inv - mu * mu;
  float rs = rsqrtf(var + 1e-5f);
  bf16* xr = x + (size_t)row * 4096;
  #define WRITE_SEG(si, vals)                                            \
  {                                                                      \
    float4 gg = ((const float4*)lng)[(si)*256 + tid];                    \
    float4 bb = ((const float4*)lnb)[(si)*256 + tid];                    \
    const float* gp = (const float*)&gg;                                 \
    const float* bp = (const float*)&bb;                                 \
    bf16x4 o;                                                            \
    _Pragma("unroll") for (int j = 0; j < 4; j++)                        \
        o[j] = (bf16)((vals[j] - mu) * rs * gp[j] + bp[j]);              \
    ((bf16x4*)xr)[(si)*256 + tid] = o;                                   \
  }
  WRITE_SEG(0, av)
  WRITE_SEG(1, bv)
  WRITE_SEG(2, hv)
  WRITE_SEG(3, dv)
  #undef WRITE_SEG
  if (tid == 0) s_ln[row] = (s - mu) * rs * lng[4096] + lnb[4096];
}

// ---------------- bf16 MFMA GEMM, 128x128 tile (EPI 0 and 2) ----------------
// EPI 0: store bf16 (t = zA@bilinear)
// EPI 2: v += b2[col]; gelu; store fp32 (out)
template <int EPI>
__global__ __launch_bounds__(256) void gemm_bt_k(
    const bf16* __restrict__ A, const bf16* __restrict__ B, int K, int Nout,
    void* __restrict__ Cout, const float* __restrict__ bias,
    const float* __restrict__ srow, const float* __restrict__ wlast) {
  __shared__ alignas(16) bf16 As[128 * 64];
  __shared__ alignas(16) bf16 Bs[128 * 64];
  const int tid = threadIdx.x;
  const int wave = tid >> 6, lane = tid & 63;
  const int wm = wave >> 1, wn = wave & 1;
  const int lrow = lane & 15, quad = lane >> 4;
  const size_t rowA0 = (size_t)blockIdx.y * 128;
  const size_t rowB0 = (size_t)blockIdx.x * 128;

  f32x4 acc[4][4] = {};

  const int lchunk = (tid & 7) ^ ((tid >> 3) & 7);
  const bf16* gA = A + (rowA0 + (tid >> 3)) * (size_t)K + lchunk * 8;
  const bf16* gB = B + (rowB0 + (tid >> 3)) * (size_t)K + lchunk * 8;

  for (int kb = 0; kb < K; kb += 64) {
    const bf16* pa = gA + kb;
    const bf16* pb = gB + kb;
    #pragma unroll
    for (int it = 0; it < 4; it++) {
      gld16(pa + (size_t)it * 32 * K, As + it * 2048 + wave * 512);
      gld16(pb + (size_t)it * 32 * K, Bs + it * 2048 + wave * 512);
    }
    __syncthreads();
    #pragma unroll
    for (int kk = 0; kk < 2; kk++) {
      const int cla = ((kk * 4 + quad) ^ (lrow & 7)) * 8;
      bf16x8 af[4], bfr[4];
      #pragma unroll
      for (int mi = 0; mi < 4; mi++)
        af[mi] = *(const bf16x8*)(As + (wm * 64 + mi * 16 + lrow) * 64 + cla);
      #pragma unroll
      for (int ni = 0; ni < 4; ni++)
        bfr[ni] = *(const bf16x8*)(Bs + (wn * 64 + ni * 16 + lrow) * 64 + cla);
      #pragma unroll
      for (int mi = 0; mi < 4; mi++)
        #pragma unroll
        for (int ni = 0; ni < 4; ni++)
          acc[mi][ni] = __builtin_amdgcn_mfma_f32_16x16x32_bf16(af[mi], bfr[ni], acc[mi][ni], 0, 0, 0);
    }
    __syncthreads();
  }

  const size_t ldc = (size_t)Nout;
  #pragma unroll
  for (int mi = 0; mi < 4; mi++) {
    size_t row = rowA0 + wm * 64 + mi * 16 + quad * 4;
    float srv[4];
    if (EPI == 1) {
      #pragma unroll
      for (int r = 0; r < 4; r++) srv[r] = srow[row + r];
    }
    #pragma unroll
    for (int ni = 0; ni < 4; ni++) {
      size_t col = rowB0 + wn * 64 + ni * 16 + lrow;
      float bvv = (EPI != 0) ? bias[col] : 0.0f;
      float wl = (EPI == 1) ? wlast[col] : 0.0f;
      #pragma unroll
      for (int r = 0; r < 4; r++) {
        float v = acc[mi][ni][r];
        if (EPI == 1) v += bvv + srv[r] * wl;
        if (EPI == 2) v += bvv;
        if (EPI != 0) v = gelu_erf(v);
        size_t idx = (row + r) * ldc + col;
        if (EPI == 2) ((float*)Cout)[idx] = v;
        else ((bf16*)Cout)[idx] = (bf16)v;
      }
    }
  }
}

// -------- 256x128-tile, 2-blocks/CU, ring-3 pipelined bf16 GEMM (EPI1) ------
// 256 threads = 4 waves (2M x 2N); wave tile 128x64 (identical per-wave code
// and register budget to the r1/r2 kernel: ~100 VGPR + 128 acc AGPR = 2
// waves/SIMD). BK=32 tiles in a ring of 3 LDS buffers -> LDS = 72 KiB ->
// TWO blocks resident per CU. Each 256-thread block = 4 waves = 1 wave per
// SIMD, so every SIMD runs one wave from each of two INDEPENDENT barrier
// domains: when one block drains lgkmcnt/vmcnt at its barriers, the other
// block's wave feeds the MFMA pipe (m114 overlap) -- attacking the ~35%
// neither-pipe-busy stall that r0/r1/r2 all showed (MfmaUtil pinned at 41%
// while removing VALU work and HBM traffic changed nothing).
// Per K32 tile j (buffer j%3), two phases:
//   phA: ds_read af[8]+bfr[0,1]; issue A(j+2) stage (4 gld16); bar;
//        [counted lgkm]; setprio; 16 MFMA (nlo=0); bar
//   phB: ds_read bfr[2,3]; issue B(j+2) stage (2 gld16); vmcnt(6); bar;
//        setprio; 16 MFMA (nlo=2); bar
// Ledger: tile j+2's 6 loads issue during tile j; vmcnt(6) at phB drains
// tile j+1 (leaves j+2's 6 in flight) => buffer (j+1)%3 complete before
// phA(j+1) reads it. Region reuse: stage target (j+2)%3 held tile j-1,
// whose reads finished before phA(j)'s preceding barrier. Tail stages wrap
// ko&(K-1) into consumed regions (never skipped => counts stay exact).
// Chunk swizzle: phys 16B chunk c of row r holds logical chunk c^((r>>1)&3)
// (staged via pre-swizzled global source, linear LDS dest); reads use
// quad^((lrow>>1)&3) -> 2 lanes/bank = free, 0 conflicts (same as r1/r2).
#define CFENCE asm volatile("" ::: "memory")
__global__ __launch_bounds__(256, 2) void gemm256x128_epi1_k(
    const bf16* __restrict__ A, const bf16* __restrict__ B, int K, int Nout,
    bf16* __restrict__ Cout, const float* __restrict__ bias,
    const float* __restrict__ srow, const float* __restrict__ wlast) {
  __shared__ alignas(16) bf16 As[3][8192];   // 3 x 256 rows x 32 k
  __shared__ alignas(16) bf16 Bs[3][4096];   // 3 x 128 rows x 32 k
  const int tid = threadIdx.x;
  const int wave = tid >> 6, lane = tid & 63;
  const int wm = wave >> 1, wn = wave & 1;
  const int lrow = lane & 15, quad = lane >> 4;
  const int cswz = ((quad ^ ((lrow >> 1) & 3)) << 3);

  // bijective 8x8-rectangle-per-XCD swizzle for the 32x32 grid (C=8192);
  // identity fallback otherwise (correctness never depends on the mapping).
  const int id = blockIdx.x;
  const int ncol = Nout >> 7;
  const int nrow = (int)(gridDim.x / ncol);
  int bxt, byt;
  if (ncol == 32 && nrow == 32) {
    const int xcd = id & 7, k = id >> 3;
    const int rect = k >> 6, pos = k & 63;
    byt = ((xcd >> 1) << 3) + (pos >> 3);
    bxt = ((xcd & 1) << 4) + (rect << 3) + (pos & 7);
  } else {
    bxt = id % ncol;
    byt = id / ncol;
  }
  const size_t rowA0 = (size_t)byt * 256;
  const size_t rowB0 = (size_t)bxt * 128;
  const int Kmask = K - 1;
  const size_t Ksz = (size_t)K;

  // staging: thread t -> row t>>2 (within 64-row slab), phys chunk t&3;
  // global source fetches the logical chunk for that phys slot (rule #21)
  const int sq = (tid & 3) ^ ((tid >> 3) & 3);
  const bf16* gA = A + (rowA0 + (tid >> 2)) * Ksz + sq * 8;
  const bf16* gB = B + (rowB0 + (tid >> 2)) * Ksz + sq * 8;
  const int wofs = wave * 512;  // 64 lanes x 8 bf16 per wave per gld16

  f32x4 acc[8][4] = {};

#define STG_A3(rb, ko) { const bf16* s_ = gA + ((ko) & Kmask);           \
    gld16(s_,             &As[rb][0 * 2048 + wofs]);                     \
    gld16(s_ +  64 * Ksz, &As[rb][1 * 2048 + wofs]);                     \
    gld16(s_ + 128 * Ksz, &As[rb][2 * 2048 + wofs]);                     \
    gld16(s_ + 192 * Ksz, &As[rb][3 * 2048 + wofs]); }
#define STG_B3(rb, ko) { const bf16* s_ = gB + ((ko) & Kmask);           \
    gld16(s_,             &Bs[rb][0 * 2048 + wofs]);                     \
    gld16(s_ +  64 * Ksz, &Bs[rb][1 * 2048 + wofs]); }

  bf16x8 af[8], bfr[2];
  const int arow = wm * 128 + lrow;
  const int brow = wn * 64 + lrow;

#define LD_A3(rb) { _Pragma("unroll") for (int mi = 0; mi < 8; mi++)     \
    af[mi] = *(const bf16x8*)(&As[rb][(arow + mi * 16) * 32 + cswz]); }
#define LD_B3(rb, nlo) { _Pragma("unroll") for (int nj = 0; nj < 2; nj++) \
    bfr[nj] = *(const bf16x8*)(&Bs[rb][(brow + ((nlo) + nj) * 16) * 32 + cswz]); }
#define MFMA_HALF(nlo) { _Pragma("unroll") for (int mi = 0; mi < 8; mi++) {           \
    acc[mi][nlo] = __builtin_amdgcn_mfma_f32_16x16x32_bf16(af[mi], bfr[0], acc[mi][nlo], 0, 0, 0);       \
    acc[mi][(nlo)+1] = __builtin_amdgcn_mfma_f32_16x16x32_bf16(af[mi], bfr[1], acc[mi][(nlo)+1], 0, 0, 0); } }
#define TILE(rb, rs, ko) {                                               \
    LD_B3(rb, 0)                                                         \
    LD_A3(rb)                                                            \
    STG_A3(rs, ko)                                                       \
    CFENCE;                                                              \
    __builtin_amdgcn_s_barrier();                                        \
    CFENCE;                                                              \
    __builtin_amdgcn_s_setprio(1);                                       \
    MFMA_HALF(0)                                                         \
    __builtin_amdgcn_s_setprio(0);                                       \
    CFENCE;                                                              \
    __builtin_amdgcn_s_barrier();                                        \
    CFENCE;                                                              \
    LD_B3(rb, 2)                                                         \
    STG_B3(rs, ko)                                                       \
    asm volatile("s_waitcnt vmcnt(6)" ::: "memory");                     \
    CFENCE;                                                              \
    __builtin_amdgcn_s_barrier();                                        \
    CFENCE;                                                              \
    __builtin_amdgcn_s_setprio(1);                                       \
    MFMA_HALF(2)                                                         \
    __builtin_amdgcn_s_setprio(0);                                       \
    CFENCE;                                                              \
    __builtin_amdgcn_s_barrier();                                        \
    CFENCE; }

  // prologue: stage tiles 0,1 (12 loads); wait tile 0 (leave tile 1 in flight)
  STG_A3(0, 0)  STG_B3(0, 0)
  STG_A3(1, 32) STG_B3(1, 32)
  asm volatile("s_waitcnt vmcnt(6)" ::: "memory");
  __builtin_amdgcn_s_barrier();
  CFENCE;

  // K/32 = 128 tiles = 42 triples + 2 tail tiles (ring indices static)
  int kb = 64;
  #pragma unroll 1
  for (int i = 0; i < 42; ++i, kb += 96) {
    TILE(0, 2, kb)
    TILE(1, 0, kb + 32)
    TILE(2, 1, kb + 64)
  }
  TILE(0, 2, kb)        // tile 126; stage wraps to k=0 (dead, keeps counts)
  TILE(1, 0, kb + 32)   // tile 127; stage wraps to k=32 (dead)
  asm volatile("s_waitcnt vmcnt(0)" ::: "memory");
#undef TILE
#undef MFMA_HALF
#undef LD_B3
#undef LD_A3
#undef STG_B3
#undef STG_A3

  const size_t ldc = (size_t)Nout;
  #pragma unroll
  for (int mi = 0; mi < 8; mi++) {
    size_t row = rowA0 + wm * 128 + mi * 16 + quad * 4;
    float srv[4];
    #pragma unroll
    for (int r = 0; r < 4; r++) srv[r] = srow[row + r];
    #pragma unroll
    for (int ni = 0; ni < 4; ni++) {
      size_t col = rowB0 + wn * 64 + ni * 16 + lrow;
      float bvv = bias[col];
      float wl = wlast[col];
      #pragma unroll
      for (int r = 0; r < 4; r++) {
        float v = acc[mi][ni][r] + bvv + srv[r] * wl;
        v = gelu_erf(v);
        Cout[(row + r) * ldc + col] = (bf16)v;
      }
    }
  }
}

extern "C" void kernel_launch(void* const* d_in, const int* in_sizes, int n_in,
                              void* d_out, int out_size, void* d_ws, size_t ws_size,
                              hipStream_t stream) {
  const float* zA  = (const float*)d_in[0];
  const float* zB  = (const float*)d_in[1];
  const float* bil = (const float*)d_in[2];
  const float* lng = (const float*)d_in[3];
  const float* lnb = (const float*)d_in[4];
  const float* W1  = (const float*)d_in[5];
  const float* b1  = (const float*)d_in[6];
  const float* W2  = (const float*)d_in[7];
  const float* b2  = (const float*)d_in[8];
  float* out = (float*)d_out;

  // ---- workspace layout (adaptive row-chunking) ----
  char* ws = (char*)d_ws;
  const size_t SZ_BILT = (size_t)DDIM * DDIM * 2;        //  2 MiB
  const size_t SZ_W1T  = (size_t)4096 * 4096 * 2;        // 32 MiB
  const size_t SZ_W2T  = (size_t)DDIM * HIDD * 2;        //  8 MiB
  const size_t PERSIST = SZ_BILT + SZ_W1T + SZ_W2T;      // 42 MiB

  int C = 0;
  for (int cand = NROWS; cand >= 512; cand >>= 1) {
    size_t need = PERSIST + (size_t)16384 * cand + (size_t)4 * cand + 1024;
    if (need <= ws_size) { C = cand; break; }
  }
  if (C == 0) return;  // workspace hopelessly small — leave poison (fail loudly)

  bf16* bilT = (bf16*)ws;
  bf16* W1T  = (bf16*)(ws + SZ_BILT);
  bf16* W2T  = (bf16*)(ws + SZ_BILT + SZ_W1T);
  char* dyn  = ws + PERSIST;
  bf16*  r1    = (bf16*)dyn;                              // region1: zA_bf|t_bf -> h
  bf16*  zA_bf = r1;                                      // [C,1024] bf16
  bf16*  t_bf  = r1 + (size_t)C * 1024;                   // [C,1024] bf16
  bf16*  h_bf  = r1;                                      // [C,4096] bf16 (overlays after rowfuse)
  bf16*  x_bf  = (bf16*)(dyn + (size_t)8192 * C);         // [C,4096] bf16
  float* s_ln  = (float*)(dyn + (size_t)16384 * C);       // [C] fp32

  dim3 tb(32, 8);
  transpose_cast_k<<<dim3(DDIM / 32, DDIM / 32), tb, 0, stream>>>(bil, bilT, DDIM, DDIM);
  transpose_cast_k<<<dim3(HIDD / 32, 4096 / 32), tb, 0, stream>>>(W1, W1T, 4096, HIDD);
  transpose_cast_k<<<dim3(DDIM / 32, HIDD / 32), tb, 0, stream>>>(W2, W2T, HIDD, DDIM);

  for (int r0 = 0; r0 < NROWS; r0 += C) {
    const float* zAc = zA + (size_t)r0 * DDIM;
    const float* zBc = zB + (size_t)r0 * DDIM;

    // cast zA chunk -> bf16
    cast_bf16_k<<<(C * DDIM / 4) / 256, 256, 0, stream>>>(zAc, zA_bf);

    // t = zA @ bilinear   [C, DDIM]
    gemm_bt_k<0><<<dim3(DDIM / 128, C / 128), 256, 0, stream>>>(
        zA_bf, bilT, DDIM, DDIM, t_bf, nullptr, nullptr, nullptr);

    // had/diff/s + LayerNorm -> x_bf, s_ln
    rowfuse_k<<<C, 256, 0, stream>>>(zAc, zBc, t_bf, lng, lnb, x_bf, s_ln);

    // h = gelu(x @ W1 + b1 + s_ln*W1_last)  [C, HIDD]
    // 256x128 tiles, 256 threads, 2 blocks/CU (independent barrier domains)
    gemm256x128_epi1_k<<<dim3((HIDD / 128) * (C / 256)), 256, 0, stream>>>(
        x_bf, W1T, 4096, HIDD, h_bf, b1, s_ln, W1 + (size_t)4096 * HIDD);

    // out = gelu(h @ W2 + b2)   [C, DDIM]
    gemm_bt_k<2><<<dim3(DDIM / 128, C / 128), 256, 0, stream>>>(
        h_bf, W2T, 4096, DDIM, out + (size_t)r0 * DDIM, b2, nullptr, nullptr);
  }
}